// Round 10
// baseline (94.920 us; speedup 1.0000x reference)
//
#include <hip/hip_runtime.h>
#include <hip/hip_cooperative_groups.h>
#include <cstdint>

namespace cg = cooperative_groups;

#define NPTS 512
#define DIM 256
#define NBLK 256
#define TK 32
#define LDB 264             // bf16 elements per LDS row (padded)
#define MARGIN_F 0.2f
#define FIX_SCALE 1073741824.0   // 2^30
#define SUM_BITS 42
#define CNT_SHIFT 42
#define DONE_SHIFT 56

typedef __attribute__((ext_vector_type(8))) short bf16x8;   // 8 bf16 = 4 VGPR
typedef __attribute__((ext_vector_type(4))) float f32x4;

__device__ __forceinline__ uint32_t rotl32(uint32_t x, uint32_t r) {
  return (x << r) | (x >> (32u - r));
}

__device__ __forceinline__ ushort f2bf(float f) {   // RNE float->bf16
  uint32_t u = __float_as_uint(f);
  return (ushort)((u + 0x7FFFu + ((u >> 16) & 1u)) >> 16);
}
__device__ __forceinline__ float bf2f(ushort h) {
  return __uint_as_float(((uint32_t)h) << 16);
}

// JAX threefry2x32, key (0, 42), partitionable mode: bits = out0 ^ out1,
// counter x = (hi32(m)=0, lo32(m)=m). Verified bit-exact (absmax 0.0, r1-r9).
__device__ __forceinline__ uint32_t threefry_bits(uint32_t c1) {
  const uint32_t k0 = 0u, k1 = 42u;
  const uint32_t k2 = k0 ^ k1 ^ 0x1BD11BDAu;
  uint32_t x0 = 0u + k0;
  uint32_t x1 = c1 + k1;
#define TFR(r) { x0 += x1; x1 = rotl32(x1, r); x1 ^= x0; }
  TFR(13u) TFR(15u) TFR(26u) TFR(6u)
  x0 += k1; x1 += k2 + 1u;
  TFR(17u) TFR(29u) TFR(16u) TFR(24u)
  x0 += k2; x1 += k0 + 2u;
  TFR(13u) TFR(15u) TFR(26u) TFR(6u)
  x0 += k0; x1 += k1 + 3u;
  TFR(17u) TFR(29u) TFR(16u) TFR(24u)
  x0 += k1; x1 += k2 + 4u;
  TFR(13u) TFR(15u) TFR(26u) TFR(6u)
  x0 += k2; x1 += k0 + 5u;
#undef TFR
  return x0 ^ x1;
}

// Fused (cooperative): Phase A = bf16-split MFMA Gram tile (round 9 verbatim),
// grid-wide sync, Phase B = semi-hard scan for anchors 2b,2b+1 (round 9
// verbatim). One dispatch; gsum zeroed by block 0 pre-sync.
__global__ __launch_bounds__(512) void triplet_fused(
    const float* __restrict__ emb,
    const int* __restrict__ labels,
    float* __restrict__ G,
    float* __restrict__ dg,
    unsigned long long* __restrict__ gsum,
    float* __restrict__ out)
{
  __shared__ __align__(16) ushort Ahi[TK][LDB];
  __shared__ __align__(16) ushort Alo[TK][LDB];
  __shared__ __align__(16) ushort Bhi[TK][LDB];
  __shared__ __align__(16) ushort Blo[TK][LDB];
  __shared__ float sd0[NPTS];
  __shared__ float sd1[NPTS];
  __shared__ int   slab[NPTS];
  __shared__ int   plist[256];
  __shared__ int   pcnt;
  __shared__ unsigned long long wsum[8], wcnt[8];

  const int b = blockIdx.x;
  const int ti = b >> 4, tj = b & 15;
  const int t = threadIdx.x;
  const int wave = t >> 6;
  const int lane = t & 63;

  if (b == 0 && t == 0) *gsum = 0ull;

  // ================= Phase A: Gram tile (round 9 verbatim) =================
  #pragma unroll
  for (int q = 0; q < 4; ++q) {
    const int idx = (q << 9) + t;       // 0..2047
    const int r = idx >> 6;             // row 0..31
    const int c4 = idx & 63;            // float4 within row
    const float4 va = *reinterpret_cast<const float4*>(emb + (ti * TK + r) * DIM + c4 * 4);
    const float4 vb = (ti == tj) ? va
        : *reinterpret_cast<const float4*>(emb + (tj * TK + r) * DIM + c4 * 4);
    const float af[4] = {va.x, va.y, va.z, va.w};
    const float bf[4] = {vb.x, vb.y, vb.z, vb.w};
    #pragma unroll
    for (int e = 0; e < 4; ++e) {
      const int c = c4 * 4 + e;
      const ushort ah = f2bf(af[e]);
      Ahi[r][c] = ah;
      Alo[r][c] = f2bf(af[e] - bf2f(ah));
      const ushort bh = f2bf(bf[e]);
      Bhi[r][c] = bh;
      Blo[r][c] = f2bf(bf[e] - bf2f(bh));
    }
  }
  __syncthreads();

  if (wave < 4) {
    const int qr = wave >> 1, qc = wave & 1;
    const int frow = qr * 16 + (lane & 15);
    const int fcol = qc * 16 + (lane & 15);
    const int kg = lane >> 4;

    f32x4 acc = {0.f, 0.f, 0.f, 0.f};
    #pragma unroll
    for (int s = 0; s < 8; ++s) {
      const int kb = s * 32 + kg * 8;
      const bf16x8 ah = *reinterpret_cast<const bf16x8*>(&Ahi[frow][kb]);
      const bf16x8 al = *reinterpret_cast<const bf16x8*>(&Alo[frow][kb]);
      const bf16x8 bh = *reinterpret_cast<const bf16x8*>(&Bhi[fcol][kb]);
      const bf16x8 bl = *reinterpret_cast<const bf16x8*>(&Blo[fcol][kb]);
      acc = __builtin_amdgcn_mfma_f32_16x16x32_bf16(ah, bh, acc, 0, 0, 0);
      acc = __builtin_amdgcn_mfma_f32_16x16x32_bf16(ah, bl, acc, 0, 0, 0);
      acc = __builtin_amdgcn_mfma_f32_16x16x32_bf16(al, bh, acc, 0, 0, 0);
    }

    const int lc = qc * 16 + (lane & 15);
    #pragma unroll
    for (int j = 0; j < 4; ++j) {
      const int lr = qr * 16 + (lane >> 4) * 4 + j;
      G[(ti * TK + lr) * NPTS + (tj * TK + lc)] = acc[j];
      if (ti == tj && lr == lc) dg[ti * TK + lr] = acc[j];
    }
  }

  // ================= Grid-wide sync (cooperative launch) ===================
  __builtin_amdgcn_fence(__ATOMIC_RELEASE, "agent");
  cg::this_grid().sync();
  __builtin_amdgcn_fence(__ATOMIC_ACQUIRE, "agent");

  // ============= Phase B: semi-hard scan (round 9 verbatim) ================
  const int a0 = b * 2;
  const int a1 = a0 + 1;

  if (t == 0) pcnt = 0;

  {
    const float da0 = dg[a0];
    const float da1 = dg[a1];
    const float dt  = dg[t];
    const float g0 = G[a0 * NPTS + t];
    const float g1 = G[a1 * NPTS + t];
    slab[t] = labels[t];
    const float v0 = da0 + dt - 2.f * g0;
    const float v1 = da1 + dt - 2.f * g1;
    sd0[t] = v0 > 0.f ? v0 : 0.f;
    sd1[t] = v1 > 0.f ? v1 : 0.f;
  }
  __syncthreads();

  {
    const int lp = slab[t];
    if (t != a0 && lp == slab[a0]) { int k = atomicAdd(&pcnt, 1); plist[k] = t; }
    if (t != a1 && lp == slab[a1]) { int k = atomicAdd(&pcnt, 1); plist[k] = (1 << 16) | t; }
  }
  __syncthreads();

  unsigned long long lsum = 0ull, lcnt = 0ull;
  const int np = pcnt;
  for (int e = wave; e < np; e += 8) {
    const int ent = plist[e];
    const int ai = ent >> 16;
    const int p = ent & 0xffff;
    const float* drp = ai ? sd1 : sd0;
    const int ag = ai ? a1 : a0;
    const int la = slab[ag];
    const float dap = drp[p];
    const float hi = dap + MARGIN_F;
    const uint32_t base = ((uint32_t)ag << 18) | ((uint32_t)p << 9);

    int bestKey = -1, bestJ = 0;
    #pragma unroll
    for (int k = 0; k < 8; ++k) {
      const int j = lane + (k << 6);
      const float dj = drp[j];
      if (slab[j] != la && dj > dap && dj < hi) {
        const int key = (int)(threefry_bits(base + (uint32_t)j) >> 9);
        if (key > bestKey) { bestKey = key; bestJ = j; }
      }
    }
    #pragma unroll
    for (int m = 32; m; m >>= 1) {
      const int ok = __shfl_xor(bestKey, m);
      const int oj = __shfl_xor(bestJ, m);
      if (ok > bestKey || (ok == bestKey && oj < bestJ)) { bestKey = ok; bestJ = oj; }
    }
    if (lane == 0 && bestKey >= 0) {
      const float term = (dap - drp[bestJ]) + MARGIN_F;
      lsum += (unsigned long long)((double)term * FIX_SCALE + 0.5);
      lcnt += 1ull;
    }
  }

  if (lane == 0) { wsum[wave] = lsum; wcnt[wave] = lcnt; }
  __syncthreads();
  if (t == 0) {
    unsigned long long s = 0ull, c = 0ull;
    #pragma unroll
    for (int w = 0; w < 8; ++w) { s += wsum[w]; c += wcnt[w]; }
    const unsigned long long contrib =
        (1ull << DONE_SHIFT) | (c << CNT_SHIFT) | s;
    const unsigned long long old = atomicAdd(gsum, contrib);
    if ((old >> DONE_SHIFT) == (unsigned long long)(NBLK - 1)) {
      const unsigned long long tot = old + contrib;
      const unsigned long long sum = tot & ((1ull << SUM_BITS) - 1ull);
      const unsigned long long cnt = (tot >> CNT_SHIFT) & 0x3FFFull;
      const double sd = (double)sum / FIX_SCALE;
      const double cd = cnt ? (double)cnt : 1.0;
      out[0] = (float)(sd / cd);
    }
  }
}

extern "C" void kernel_launch(void* const* d_in, const int* in_sizes, int n_in,
                              void* d_out, int out_size, void* d_ws, size_t ws_size,
                              hipStream_t stream) {
  const float* emb  = (const float*)d_in[0];
  const int* labels = (const int*)d_in[1];
  float* out        = (float*)d_out;

  char* ws = (char*)d_ws;
  unsigned long long* gsum = (unsigned long long*)ws;          // 8 B
  float* dg = (float*)(ws + 2048);                             // 512 * 4 B
  float* G  = (float*)(ws + 8192);                             // 1 MB

  void* args[] = {(void*)&emb, (void*)&labels, (void*)&G, (void*)&dg,
                  (void*)&gsum, (void*)&out};
  hipLaunchCooperativeKernel((const void*)triplet_fused, dim3(NBLK), dim3(512),
                             args, 0, stream);
}

// Round 11
// 16.827 us; speedup vs baseline: 5.6411x; 5.6411x over previous
//
#include <hip/hip_runtime.h>
#include <cstdint>

#define NPTS 512
#define DIM 256
#define NBLK (NPTS / 2)
#define TK 32
#define LDB 264             // bf16 elements per LDS row (padded: 528 B/row, 16B-aligned)
#define MARGIN_F 0.2f
#define FIX_SCALE 1073741824.0   // 2^30
#define SUM_BITS 42
#define CNT_SHIFT 42
#define DONE_SHIFT 56

typedef __attribute__((ext_vector_type(8))) short bf16x8;   // 8 bf16 = 4 VGPR
typedef __attribute__((ext_vector_type(4))) float f32x4;

__device__ __forceinline__ uint32_t rotl32(uint32_t x, uint32_t r) {
  return (x << r) | (x >> (32u - r));
}

__device__ __forceinline__ ushort f2bf(float f) {   // RNE float->bf16
  uint32_t u = __float_as_uint(f);
  return (ushort)((u + 0x7FFFu + ((u >> 16) & 1u)) >> 16);
}
__device__ __forceinline__ float bf2f(ushort h) {
  return __uint_as_float(((uint32_t)h) << 16);
}

// Split 8 floats into packed hi/lo bf16 uint4s (RNE, lo = f - hi exactly split).
__device__ __forceinline__ void split8(const float4 v0, const float4 v1,
                                       uint4& hi, uint4& lo) {
  const float f[8] = {v0.x, v0.y, v0.z, v0.w, v1.x, v1.y, v1.z, v1.w};
  uint32_t h[8], l[8];
  #pragma unroll
  for (int e = 0; e < 8; ++e) {
    const ushort hh = f2bf(f[e]);
    h[e] = hh;
    l[e] = f2bf(f[e] - bf2f(hh));
  }
  hi.x = h[0] | (h[1] << 16); hi.y = h[2] | (h[3] << 16);
  hi.z = h[4] | (h[5] << 16); hi.w = h[6] | (h[7] << 16);
  lo.x = l[0] | (l[1] << 16); lo.y = l[2] | (l[3] << 16);
  lo.z = l[4] | (l[5] << 16); lo.w = l[6] | (l[7] << 16);
}

// JAX threefry2x32, key (0, 42), partitionable mode: bits = out0 ^ out1,
// counter x = (hi32(m)=0, lo32(m)=m). Verified bit-exact (absmax 0.0, r1-r10).
__device__ __forceinline__ uint32_t threefry_bits(uint32_t c1) {
  const uint32_t k0 = 0u, k1 = 42u;
  const uint32_t k2 = k0 ^ k1 ^ 0x1BD11BDAu;
  uint32_t x0 = 0u + k0;
  uint32_t x1 = c1 + k1;
#define TFR(r) { x0 += x1; x1 = rotl32(x1, r); x1 ^= x0; }
  TFR(13u) TFR(15u) TFR(26u) TFR(6u)
  x0 += k1; x1 += k2 + 1u;
  TFR(17u) TFR(29u) TFR(16u) TFR(24u)
  x0 += k2; x1 += k0 + 2u;
  TFR(13u) TFR(15u) TFR(26u) TFR(6u)
  x0 += k0; x1 += k1 + 3u;
  TFR(17u) TFR(29u) TFR(16u) TFR(24u)
  x0 += k1; x1 += k2 + 4u;
  TFR(13u) TFR(15u) TFR(26u) TFR(6u)
  x0 += k2; x1 += k0 + 5u;
#undef TFR
  return x0 ^ x1;
}

// ---- K1: Gram via bf16-split MFMA. Block b -> 32x32 tile (b>>4, b&15). ----
// G = E.E^T ~= hi.hi^T + hi.lo^T + lo.hi^T (lo.lo ~ 2^-18 rel, dropped).
// Staging: each thread converts 8 consecutive floats -> one packed uint4 per
// array (8 ds_write_b128/thread total, was 64 ds_write_b16).
// MFMA: 3 independent accumulators (chain 24 -> 8), summed at the end.
__global__ __launch_bounds__(512) void gram_kernel(
    const float* __restrict__ emb,
    float* __restrict__ G,
    float* __restrict__ dg,
    unsigned long long* __restrict__ gsum)
{
  __shared__ __align__(16) ushort Ahi[TK][LDB];
  __shared__ __align__(16) ushort Alo[TK][LDB];
  __shared__ __align__(16) ushort Bhi[TK][LDB];
  __shared__ __align__(16) ushort Blo[TK][LDB];

  const int b = blockIdx.x;
  const int ti = b >> 4, tj = b & 15;
  const int t = threadIdx.x;
  const int wave = t >> 6;
  const int lane = t & 63;

  if (b == 0 && t == 0) *gsum = 0ull;   // replaces a memset dispatch

  // ---- stage + split-convert: 1024 8-float chunks / 512 threads = 2 each --
  #pragma unroll
  for (int iter = 0; iter < 2; ++iter) {
    const int cidx = (iter << 9) + t;   // 0..1023
    const int r = cidx >> 5;            // row 0..31
    const int c8 = cidx & 31;           // 8-float chunk within row
    const float* pa = emb + (ti * TK + r) * DIM + c8 * 8;
    const float4 a0 = *reinterpret_cast<const float4*>(pa);
    const float4 a1 = *reinterpret_cast<const float4*>(pa + 4);
    uint4 ahi, alo;
    split8(a0, a1, ahi, alo);
    *reinterpret_cast<uint4*>(&Ahi[r][c8 * 8]) = ahi;
    *reinterpret_cast<uint4*>(&Alo[r][c8 * 8]) = alo;
    uint4 bhi, blo;
    if (ti == tj) { bhi = ahi; blo = alo; }
    else {
      const float* pb = emb + (tj * TK + r) * DIM + c8 * 8;
      const float4 b0 = *reinterpret_cast<const float4*>(pb);
      const float4 b1 = *reinterpret_cast<const float4*>(pb + 4);
      split8(b0, b1, bhi, blo);
    }
    *reinterpret_cast<uint4*>(&Bhi[r][c8 * 8]) = bhi;
    *reinterpret_cast<uint4*>(&Blo[r][c8 * 8]) = blo;
  }
  __syncthreads();

  // ---- MFMA phase: waves 0-3, quadrant (qr,qc) = (wave>>1, wave&1) ----
  if (wave < 4) {
    const int qr = wave >> 1, qc = wave & 1;
    const int frow = qr * 16 + (lane & 15);   // A-fragment row
    const int fcol = qc * 16 + (lane & 15);   // B-fragment col (B^T row)
    const int kg = lane >> 4;                 // k-group 0..3

    f32x4 acc_h  = {0.f, 0.f, 0.f, 0.f};
    f32x4 acc_hl = {0.f, 0.f, 0.f, 0.f};
    f32x4 acc_lh = {0.f, 0.f, 0.f, 0.f};
    #pragma unroll
    for (int s = 0; s < 8; ++s) {
      const int kb = s * 32 + kg * 8;
      const bf16x8 ah = *reinterpret_cast<const bf16x8*>(&Ahi[frow][kb]);
      const bf16x8 al = *reinterpret_cast<const bf16x8*>(&Alo[frow][kb]);
      const bf16x8 bh = *reinterpret_cast<const bf16x8*>(&Bhi[fcol][kb]);
      const bf16x8 bl = *reinterpret_cast<const bf16x8*>(&Blo[fcol][kb]);
      acc_h  = __builtin_amdgcn_mfma_f32_16x16x32_bf16(ah, bh, acc_h,  0, 0, 0);
      acc_hl = __builtin_amdgcn_mfma_f32_16x16x32_bf16(ah, bl, acc_hl, 0, 0, 0);
      acc_lh = __builtin_amdgcn_mfma_f32_16x16x32_bf16(al, bh, acc_lh, 0, 0, 0);
    }

    // C/D layout (m89): col = lane&15, row = (lane>>4)*4 + j
    const int lc = qc * 16 + (lane & 15);
    #pragma unroll
    for (int j = 0; j < 4; ++j) {
      const int lr = qr * 16 + (lane >> 4) * 4 + j;
      const float g = (acc_h[j] + acc_hl[j]) + acc_lh[j];
      G[(ti * TK + lr) * NPTS + (tj * TK + lc)] = g;
      if (ti == tj && lr == lc) dg[ti * TK + lr] = g;
    }
  }
}

// ---- K2: semi-hard scan. One block per 2 anchors, 512 threads = 8 waves. --
__global__ __launch_bounds__(512) void semihard_kernel(
    const float* __restrict__ G,
    const float* __restrict__ dg,
    const int* __restrict__ labels,
    unsigned long long* __restrict__ gsum,
    float* __restrict__ out)
{
  __shared__ float sd0[NPTS];
  __shared__ float sd1[NPTS];
  __shared__ int   slab[NPTS];
  __shared__ int   plist[256];
  __shared__ int   pcnt;
  __shared__ unsigned long long wsum[8], wcnt[8];

  const int a0 = blockIdx.x * 2;
  const int a1 = a0 + 1;
  const int t = threadIdx.x;
  const int wave = t >> 6;
  const int lane = t & 63;

  if (t == 0) pcnt = 0;

  {
    const float da0 = dg[a0];
    const float da1 = dg[a1];
    const float dt  = dg[t];
    const float g0 = G[a0 * NPTS + t];
    const float g1 = G[a1 * NPTS + t];
    slab[t] = labels[t];
    const float v0 = da0 + dt - 2.f * g0;
    const float v1 = da1 + dt - 2.f * g1;
    sd0[t] = v0 > 0.f ? v0 : 0.f;
    sd1[t] = v1 > 0.f ? v1 : 0.f;
  }
  __syncthreads();

  {
    const int lp = slab[t];
    if (t != a0 && lp == slab[a0]) { int k = atomicAdd(&pcnt, 1); plist[k] = t; }
    if (t != a1 && lp == slab[a1]) { int k = atomicAdd(&pcnt, 1); plist[k] = (1 << 16) | t; }
  }
  __syncthreads();

  // Hoist this lane's 8 candidate slots into registers (reused across pairs).
  float d0v[8], d1v[8];
  int labv[8];
  #pragma unroll
  for (int k = 0; k < 8; ++k) {
    const int j = lane + (k << 6);
    d0v[k] = sd0[j];
    d1v[k] = sd1[j];
    labv[k] = slab[j];
  }

  unsigned long long lsum = 0ull, lcnt = 0ull;
  const int np = pcnt;
  for (int e = wave; e < np; e += 8) {
    const int ent = plist[e];
    const int ai = ent >> 16;
    const int p = ent & 0xffff;
    const int ag = ai ? a1 : a0;
    const int la = slab[ag];
    const float dap = ai ? sd1[p] : sd0[p];
    const float hi = dap + MARGIN_F;
    const uint32_t base = ((uint32_t)ag << 18) | ((uint32_t)p << 9);

    int bestKey = -1, bestJ = 0;
    #pragma unroll
    for (int k = 0; k < 8; ++k) {
      const int j = lane + (k << 6);
      const float dj = ai ? d1v[k] : d0v[k];
      if (labv[k] != la && dj > dap && dj < hi) {
        const int key = (int)(threefry_bits(base + (uint32_t)j) >> 9);
        if (key > bestKey) { bestKey = key; bestJ = j; }
      }
    }
    #pragma unroll
    for (int m = 32; m; m >>= 1) {
      const int ok = __shfl_xor(bestKey, m);
      const int oj = __shfl_xor(bestJ, m);
      if (ok > bestKey || (ok == bestKey && oj < bestJ)) { bestKey = ok; bestJ = oj; }
    }
    if (lane == 0 && bestKey >= 0) {
      const float dan = (bestJ & 64) ? ((bestJ & 128) ? 0.f : 0.f) : 0.f; // (unused)
      const float term = (dap - (ai ? sd1[bestJ] : sd0[bestJ])) + MARGIN_F;
      lsum += (unsigned long long)((double)term * FIX_SCALE + 0.5);
      lcnt += 1ull;
    }
  }

  if (lane == 0) { wsum[wave] = lsum; wcnt[wave] = lcnt; }
  __syncthreads();
  if (t == 0) {
    unsigned long long s = 0ull, c = 0ull;
    #pragma unroll
    for (int w = 0; w < 8; ++w) { s += wsum[w]; c += wcnt[w]; }
    const unsigned long long contrib =
        (1ull << DONE_SHIFT) | (c << CNT_SHIFT) | s;
    const unsigned long long old = atomicAdd(gsum, contrib);
    if ((old >> DONE_SHIFT) == (unsigned long long)(NBLK - 1)) {
      const unsigned long long tot = old + contrib;
      const unsigned long long sum = tot & ((1ull << SUM_BITS) - 1ull);
      const unsigned long long cnt = (tot >> CNT_SHIFT) & 0x3FFFull;
      const double sd = (double)sum / FIX_SCALE;
      const double cd = cnt ? (double)cnt : 1.0;
      out[0] = (float)(sd / cd);
    }
  }
}

extern "C" void kernel_launch(void* const* d_in, const int* in_sizes, int n_in,
                              void* d_out, int out_size, void* d_ws, size_t ws_size,
                              hipStream_t stream) {
  const float* emb  = (const float*)d_in[0];
  const int* labels = (const int*)d_in[1];
  float* out        = (float*)d_out;

  char* ws = (char*)d_ws;
  unsigned long long* gsum = (unsigned long long*)ws;          // 8 B
  float* dg = (float*)(ws + 2048);                             // 512 * 4 B
  float* G  = (float*)(ws + 8192);                             // 1 MB

  gram_kernel<<<dim3(256), dim3(512), 0, stream>>>(emb, G, dg, gsum);
  semihard_kernel<<<dim3(NBLK), dim3(512), 0, stream>>>(G, dg, labels, gsum, out);
}